// Round 1
// baseline (923.377 us; speedup 1.0000x reference)
//
#include <hip/hip_runtime.h>

#define DM 128
#define DE 64

static constexpr int kB = 4;
static constexpr int kN = 50000;
static constexpr int kE = 600000;
static constexpr int kNodes = kB * kN;  // 200000

// workspace layout (float units)
static constexpr size_t OFF_V    = 0;                              // nodes x 128
static constexpr size_t OFF_T    = OFF_V + (size_t)kNodes * DM;    // nodes x 64
static constexpr size_t OFF_QA   = OFF_T + (size_t)kNodes * DE;    // nodes
static constexpr size_t OFF_KA   = OFF_QA + kNodes;                // nodes
static constexpr size_t OFF_ASUM = OFF_KA + kNodes;                // nodes
static constexpr size_t OFF_S    = OFF_ASUM + kNodes;              // nodes (contiguous w/ ASUM for one memset)
static constexpr size_t OFF_AEXP = OFF_S + kNodes;                 // edges
static constexpr size_t OFF_WQA  = OFF_AEXP + kE;                  // 128
static constexpr size_t OFF_WKA  = OFF_WQA + DM;                   // 128
static constexpr size_t OFF_WEWA = OFF_WKA + DM;                   // 64
static constexpr size_t OFF_CB   = OFF_WEWA + DE;                  // 1

// K0: fold Wa through the Q/K/Ew projections. wqa = Wq@Wa etc., cb = (bq+bk+bew)·Wa
__global__ void k0_combine(const float* __restrict__ Wq, const float* __restrict__ Wk,
                           const float* __restrict__ Wew, const float* __restrict__ Wa,
                           const float* __restrict__ bq, const float* __restrict__ bk,
                           const float* __restrict__ bew, float* __restrict__ ws) {
  int t = threadIdx.x;
  if (t < DM) {
    float a = 0.f;
    for (int j = 0; j < DM; ++j) a += Wq[t * DM + j] * Wa[j];
    ws[OFF_WQA + t] = a;
  } else if (t < 2 * DM) {
    int i = t - DM;
    float a = 0.f;
    for (int j = 0; j < DM; ++j) a += Wk[i * DM + j] * Wa[j];
    ws[OFF_WKA + i] = a;
  } else if (t < 2 * DM + DE) {
    int i = t - 2 * DM;
    float a = 0.f;
    for (int j = 0; j < DM; ++j) a += Wew[i * DM + j] * Wa[j];
    ws[OFF_WEWA + i] = a;
  }
  if (t == 0) {
    float a = 0.f;
    for (int j = 0; j < DM; ++j) a += (bq[j] + bk[j] + bew[j]) * Wa[j];
    ws[OFF_CB] = a;
  }
}

// K1: V = x@Wv + bv (200000x128x128), fused qa = x·wqa, ka = x·wka.
// 64-row x 128-col tile per 256-thread block; x tile + 32-row Wv chunks in LDS.
__global__ __launch_bounds__(256) void k1_node(const float* __restrict__ x,
                                               const float* __restrict__ Wv,
                                               const float* __restrict__ bv,
                                               float* __restrict__ ws) {
  __shared__ float xs[64][132];   // +4 pad: 2-way bank alias only (free)
  __shared__ float wvs[32][132];
  const int t = threadIdx.x;
  const int row0 = blockIdx.x * 64;

  // stage x tile: 64x128 = 2048 float4, coalesced
  const float4* xg = (const float4*)(x + (size_t)row0 * DM);
  #pragma unroll
  for (int i = 0; i < 8; ++i) {
    int idx = t + i * 256;
    int r = idx >> 5, c = (idx & 31) * 4;
    *(float4*)&xs[r][c] = xg[idx];
  }
  __syncthreads();

  // qa/ka: waves 0/1 compute per-row scalars from the staged tile
  if (t < 128) {
    const int r = t & 63;
    const float* wvec = (t < 64) ? (ws + OFF_WQA) : (ws + OFF_WKA);
    float a = 0.f;
    for (int k = 0; k < DM; k += 4) {
      a += xs[r][k] * wvec[k] + xs[r][k + 1] * wvec[k + 1] +
           xs[r][k + 2] * wvec[k + 2] + xs[r][k + 3] * wvec[k + 3];
    }
    float* dstp = (t < 64) ? (ws + OFF_QA) : (ws + OFF_KA);
    dstp[row0 + r] = a;
  }

  const int tx = t & 15, ty = t >> 4;
  const int j0 = tx * 8, r0 = ty * 4;
  float acc[4][8];
  #pragma unroll
  for (int i = 0; i < 4; ++i)
    #pragma unroll
    for (int j = 0; j < 8; ++j) acc[i][j] = 0.f;

  for (int kc = 0; kc < 4; ++kc) {
    __syncthreads();  // protect wvs from previous chunk's readers
    const float4* wg = (const float4*)(Wv + (size_t)kc * 32 * DM);
    #pragma unroll
    for (int i = 0; i < 4; ++i) {
      int idx = t + i * 256;
      int r = idx >> 5, c = (idx & 31) * 4;
      *(float4*)&wvs[r][c] = wg[idx];
    }
    __syncthreads();
    const int kb = kc * 32;
    #pragma unroll
    for (int kk = 0; kk < 32; kk += 4) {
      float xv[4][4];
      #pragma unroll
      for (int i = 0; i < 4; ++i) {
        float4 tmp = *(const float4*)&xs[r0 + i][kb + kk];
        xv[i][0] = tmp.x; xv[i][1] = tmp.y; xv[i][2] = tmp.z; xv[i][3] = tmp.w;
      }
      #pragma unroll
      for (int d = 0; d < 4; ++d) {
        float4 w0 = *(const float4*)&wvs[kk + d][j0];
        float4 w1 = *(const float4*)&wvs[kk + d][j0 + 4];
        float wj[8] = {w0.x, w0.y, w0.z, w0.w, w1.x, w1.y, w1.z, w1.w};
        #pragma unroll
        for (int i = 0; i < 4; ++i)
          #pragma unroll
          for (int j = 0; j < 8; ++j) acc[i][j] += xv[i][d] * wj[j];
      }
    }
  }

  const float4 bv0 = *(const float4*)&bv[j0];
  const float4 bv1 = *(const float4*)&bv[j0 + 4];
  float* Vp = ws + OFF_V + (size_t)row0 * DM;
  #pragma unroll
  for (int i = 0; i < 4; ++i) {
    float4 o0 = make_float4(acc[i][0] + bv0.x, acc[i][1] + bv0.y,
                            acc[i][2] + bv0.z, acc[i][3] + bv0.w);
    float4 o1 = make_float4(acc[i][4] + bv1.x, acc[i][5] + bv1.y,
                            acc[i][6] + bv1.z, acc[i][7] + bv1.w);
    *(float4*)&Vp[(size_t)(r0 + i) * DM + j0] = o0;
    *(float4*)&Vp[(size_t)(r0 + i) * DM + j0 + 4] = o1;
  }
}

// K2: per-edge logit -> exp -> atomic segment sum over (b,dst)
__global__ __launch_bounds__(256) void k2_edge1(const int* __restrict__ ei,
                                                const int* __restrict__ bidx,
                                                const float* __restrict__ eemb,
                                                float* __restrict__ ws) {
  __shared__ float wewa_s[DE];
  __shared__ float cb_s;
  int t = threadIdx.x;
  if (t < DE) wewa_s[t] = ws[OFF_WEWA + t];
  if (t == DE) cb_s = ws[OFF_CB];
  __syncthreads();
  int e = blockIdx.x * 256 + t;
  if (e >= kE) return;
  int s = ei[e];
  int d = ei[kE + e];
  int b = bidx[e];
  const float4* emb = (const float4*)(eemb + (size_t)e * DE);
  float a = 0.f;
  #pragma unroll
  for (int i = 0; i < 16; ++i) {
    float4 v = emb[i];
    a += v.x * wewa_s[i * 4] + v.y * wewa_s[i * 4 + 1] +
         v.z * wewa_s[i * 4 + 2] + v.w * wewa_s[i * 4 + 3];
  }
  float logit = (ws[OFF_QA + b * kN + s] + ws[OFF_KA + b * kN + d] + a + cb_s) * 0.25f;
  float ex = __expf(logit);
  ws[OFF_AEXP + e] = ex;
  unsafeAtomicAdd(&ws[OFF_ASUM + b * kN + d], ex);
}

// K3: wave-per-edge scatter: out1 += a*V[dst], T += a*emb, S += a
__global__ __launch_bounds__(256) void k3_edge2(const int* __restrict__ ei,
                                                const int* __restrict__ bidx,
                                                const float* __restrict__ eemb,
                                                float* __restrict__ ws,
                                                float* __restrict__ out) {
  const int lane = threadIdx.x & 63;
  const int wid = (blockIdx.x * 256 + threadIdx.x) >> 6;
  const int nw = (gridDim.x * 256) >> 6;
  const float* V = ws + OFF_V;
  float* T = ws + OFF_T;
  float* S = ws + OFF_S;
  const float* aexp = ws + OFF_AEXP;
  const float* asum = ws + OFF_ASUM;
  for (int e = wid; e < kE; e += nw) {
    int s = ei[e];
    int d = ei[kE + e];
    int b = bidx[e];
    int gs = b * kN + s;
    int gd = b * kN + d;
    float alpha = aexp[e] / (asum[gd] + 1e-9f);
    float embv = eemb[(size_t)e * DE + lane];
    unsafeAtomicAdd(&T[(size_t)gs * DE + lane], alpha * embv);
    float v0 = V[(size_t)gd * DM + lane];
    float v1 = V[(size_t)gd * DM + 64 + lane];
    unsafeAtomicAdd(&out[(size_t)gs * DM + lane], alpha * v0);
    unsafeAtomicAdd(&out[(size_t)gs * DM + 64 + lane], alpha * v1);
    if (lane == 0) unsafeAtomicAdd(&S[gs], alpha);
  }
}

// K4: out = out1 + T@Wev + S*bev  (200000x64x128 GEMM, epilogue fused in-place)
__global__ __launch_bounds__(256) void k4_final(const float* __restrict__ Wev,
                                                const float* __restrict__ bev,
                                                float* __restrict__ ws,
                                                float* __restrict__ out) {
  __shared__ float ts[64][68];
  __shared__ float wes[64][132];
  __shared__ float bevs[DM];
  const int t = threadIdx.x;
  const int row0 = blockIdx.x * 64;
  const float* T = ws + OFF_T;
  const float* S = ws + OFF_S;

  const float4* tg = (const float4*)(T + (size_t)row0 * DE);
  #pragma unroll
  for (int i = 0; i < 4; ++i) {
    int idx = t + i * 256;
    int r = idx >> 4, c = (idx & 15) * 4;
    *(float4*)&ts[r][c] = tg[idx];
  }
  const float4* wg = (const float4*)Wev;
  #pragma unroll
  for (int i = 0; i < 8; ++i) {
    int idx = t + i * 256;
    int r = idx >> 5, c = (idx & 31) * 4;
    *(float4*)&wes[r][c] = wg[idx];
  }
  if (t < DM) bevs[t] = bev[t];
  __syncthreads();

  const int tx = t & 15, ty = t >> 4;
  const int j0 = tx * 8, r0 = ty * 4;
  float acc[4][8];
  #pragma unroll
  for (int i = 0; i < 4; ++i)
    #pragma unroll
    for (int j = 0; j < 8; ++j) acc[i][j] = 0.f;

  #pragma unroll
  for (int kk = 0; kk < DE; kk += 4) {
    float xv[4][4];
    #pragma unroll
    for (int i = 0; i < 4; ++i) {
      float4 tmp = *(const float4*)&ts[r0 + i][kk];
      xv[i][0] = tmp.x; xv[i][1] = tmp.y; xv[i][2] = tmp.z; xv[i][3] = tmp.w;
    }
    #pragma unroll
    for (int d = 0; d < 4; ++d) {
      float4 w0 = *(const float4*)&wes[kk + d][j0];
      float4 w1 = *(const float4*)&wes[kk + d][j0 + 4];
      float wj[8] = {w0.x, w0.y, w0.z, w0.w, w1.x, w1.y, w1.z, w1.w};
      #pragma unroll
      for (int i = 0; i < 4; ++i)
        #pragma unroll
        for (int j = 0; j < 8; ++j) acc[i][j] += xv[i][d] * wj[j];
    }
  }

  #pragma unroll
  for (int i = 0; i < 4; ++i) {
    size_t g = (size_t)(row0 + r0 + i);
    float sv = S[g];
    float4 o0 = *(const float4*)&out[g * DM + j0];
    float4 o1 = *(const float4*)&out[g * DM + j0 + 4];
    o0.x = acc[i][0] + o0.x + sv * bevs[j0 + 0];
    o0.y = acc[i][1] + o0.y + sv * bevs[j0 + 1];
    o0.z = acc[i][2] + o0.z + sv * bevs[j0 + 2];
    o0.w = acc[i][3] + o0.w + sv * bevs[j0 + 3];
    o1.x = acc[i][4] + o1.x + sv * bevs[j0 + 4];
    o1.y = acc[i][5] + o1.y + sv * bevs[j0 + 5];
    o1.z = acc[i][6] + o1.z + sv * bevs[j0 + 6];
    o1.w = acc[i][7] + o1.w + sv * bevs[j0 + 7];
    *(float4*)&out[g * DM + j0] = o0;
    *(float4*)&out[g * DM + j0 + 4] = o1;
  }
}

extern "C" void kernel_launch(void* const* d_in, const int* in_sizes, int n_in,
                              void* d_out, int out_size, void* d_ws, size_t ws_size,
                              hipStream_t stream) {
  const float* x    = (const float*)d_in[0];
  const int*   ei   = (const int*)d_in[1];
  const float* eemb = (const float*)d_in[2];
  const int*   bidx = (const int*)d_in[3];
  // d_in[4] = n_heads (unused; d_h = 16 -> scale 0.25 hard-coded)
  const float* Wq  = (const float*)d_in[5];
  const float* bq  = (const float*)d_in[6];
  const float* Wk  = (const float*)d_in[7];
  const float* bk  = (const float*)d_in[8];
  const float* Wv  = (const float*)d_in[9];
  const float* bv  = (const float*)d_in[10];
  const float* Wew = (const float*)d_in[11];
  const float* bew = (const float*)d_in[12];
  const float* Wev = (const float*)d_in[13];
  const float* bev = (const float*)d_in[14];
  const float* Wa  = (const float*)d_in[15];
  float* ws  = (float*)d_ws;
  float* out = (float*)d_out;

  // zero accumulators: d_out (=out1), T, att_sum+S (contiguous)
  hipMemsetAsync(out, 0, (size_t)out_size * sizeof(float), stream);
  hipMemsetAsync(ws + OFF_T, 0, (size_t)kNodes * DE * sizeof(float), stream);
  hipMemsetAsync(ws + OFF_ASUM, 0, (size_t)kNodes * 2 * sizeof(float), stream);

  k0_combine<<<1, 320, 0, stream>>>(Wq, Wk, Wew, Wa, bq, bk, bew, ws);
  k1_node<<<kNodes / 64, 256, 0, stream>>>(x, Wv, bv, ws);
  k2_edge1<<<(kE + 255) / 256, 256, 0, stream>>>(ei, bidx, eemb, ws);
  k3_edge2<<<4096, 256, 0, stream>>>(ei, bidx, eemb, ws, out);
  k4_final<<<kNodes / 64, 256, 0, stream>>>(Wev, bev, ws, out);
}

// Round 2
// 750.468 us; speedup vs baseline: 1.2304x; 1.2304x over previous
//
#include <hip/hip_runtime.h>

#define DM 128
#define DE 64

static constexpr int kB = 4;
static constexpr int kN = 50000;
static constexpr int kE = 600000;
static constexpr int kNodes = kB * kN;  // 200000

// workspace layout (float units; 4B-aligned ints share the arena)
static constexpr size_t OFF_V    = 0;                               // nodes x 128
static constexpr size_t OFF_QA   = OFF_V + (size_t)kNodes * DM;     // nodes
static constexpr size_t OFF_KA   = OFF_QA + kNodes;                 // nodes
static constexpr size_t OFF_ASUM = OFF_KA + kNodes;                 // nodes
static constexpr size_t OFF_AEXP = OFF_ASUM + kNodes;               // edges
static constexpr size_t OFF_CNT  = OFF_AEXP + kE;                   // nodes (int)
static constexpr size_t OFF_OFFS = OFF_CNT + kNodes;                // nodes (int; loff -> final off)
static constexpr size_t OFF_POS  = OFF_OFFS + kNodes;               // edges (int)
static constexpr size_t OFF_BSUM = OFF_POS + kE;                    // 1024 (int)
static constexpr size_t OFF_BPRE = OFF_BSUM + 1024;                 // 1024 (int)
static constexpr size_t OFF_REC  = OFF_BPRE + 1024;                 // edges x float4 (16B aligned)
static constexpr size_t OFF_WQA  = OFF_REC + (size_t)kE * 4;        // 128
static constexpr size_t OFF_WKA  = OFF_WQA + DM;                    // 128
static constexpr size_t OFF_WEWA = OFF_WKA + DM;                    // 64
static constexpr size_t OFF_CB   = OFF_WEWA + DE;                   // 1

static constexpr int kScanBlocks = (kNodes + 255) / 256;  // 782

// K0: fold Wa through the Q/K/Ew projections. wqa = Wq@Wa etc., cb = (bq+bk+bew)·Wa
__global__ void k0_combine(const float* __restrict__ Wq, const float* __restrict__ Wk,
                           const float* __restrict__ Wew, const float* __restrict__ Wa,
                           const float* __restrict__ bq, const float* __restrict__ bk,
                           const float* __restrict__ bew, float* __restrict__ ws) {
  int t = threadIdx.x;
  if (t < DM) {
    float a = 0.f;
    for (int j = 0; j < DM; ++j) a += Wq[t * DM + j] * Wa[j];
    ws[OFF_WQA + t] = a;
  } else if (t < 2 * DM) {
    int i = t - DM;
    float a = 0.f;
    for (int j = 0; j < DM; ++j) a += Wk[i * DM + j] * Wa[j];
    ws[OFF_WKA + i] = a;
  } else if (t < 2 * DM + DE) {
    int i = t - 2 * DM;
    float a = 0.f;
    for (int j = 0; j < DM; ++j) a += Wew[i * DM + j] * Wa[j];
    ws[OFF_WEWA + i] = a;
  }
  if (t == 0) {
    float a = 0.f;
    for (int j = 0; j < DM; ++j) a += (bq[j] + bk[j] + bew[j]) * Wa[j];
    ws[OFF_CB] = a;
  }
}

// K1: V = x@Wv + bv (200000x128x128), fused qa = x·wqa, ka = x·wka.
__global__ __launch_bounds__(256) void k1_node(const float* __restrict__ x,
                                               const float* __restrict__ Wv,
                                               const float* __restrict__ bv,
                                               float* __restrict__ ws) {
  __shared__ float xs[64][132];
  __shared__ float wvs[32][132];
  const int t = threadIdx.x;
  const int row0 = blockIdx.x * 64;

  const float4* xg = (const float4*)(x + (size_t)row0 * DM);
  #pragma unroll
  for (int i = 0; i < 8; ++i) {
    int idx = t + i * 256;
    int r = idx >> 5, c = (idx & 31) * 4;
    *(float4*)&xs[r][c] = xg[idx];
  }
  __syncthreads();

  if (t < 128) {
    const int r = t & 63;
    const float* wvec = (t < 64) ? (ws + OFF_WQA) : (ws + OFF_WKA);
    float a = 0.f;
    for (int k = 0; k < DM; k += 4) {
      a += xs[r][k] * wvec[k] + xs[r][k + 1] * wvec[k + 1] +
           xs[r][k + 2] * wvec[k + 2] + xs[r][k + 3] * wvec[k + 3];
    }
    float* dstp = (t < 64) ? (ws + OFF_QA) : (ws + OFF_KA);
    dstp[row0 + r] = a;
  }

  const int tx = t & 15, ty = t >> 4;
  const int j0 = tx * 8, r0 = ty * 4;
  float acc[4][8];
  #pragma unroll
  for (int i = 0; i < 4; ++i)
    #pragma unroll
    for (int j = 0; j < 8; ++j) acc[i][j] = 0.f;

  for (int kc = 0; kc < 4; ++kc) {
    __syncthreads();
    const float4* wg = (const float4*)(Wv + (size_t)kc * 32 * DM);
    #pragma unroll
    for (int i = 0; i < 4; ++i) {
      int idx = t + i * 256;
      int r = idx >> 5, c = (idx & 31) * 4;
      *(float4*)&wvs[r][c] = wg[idx];
    }
    __syncthreads();
    const int kb = kc * 32;
    #pragma unroll
    for (int kk = 0; kk < 32; kk += 4) {
      float xv[4][4];
      #pragma unroll
      for (int i = 0; i < 4; ++i) {
        float4 tmp = *(const float4*)&xs[r0 + i][kb + kk];
        xv[i][0] = tmp.x; xv[i][1] = tmp.y; xv[i][2] = tmp.z; xv[i][3] = tmp.w;
      }
      #pragma unroll
      for (int d = 0; d < 4; ++d) {
        float4 w0 = *(const float4*)&wvs[kk + d][j0];
        float4 w1 = *(const float4*)&wvs[kk + d][j0 + 4];
        float wj[8] = {w0.x, w0.y, w0.z, w0.w, w1.x, w1.y, w1.z, w1.w};
        #pragma unroll
        for (int i = 0; i < 4; ++i)
          #pragma unroll
          for (int j = 0; j < 8; ++j) acc[i][j] += xv[i][d] * wj[j];
      }
    }
  }

  const float4 bv0 = *(const float4*)&bv[j0];
  const float4 bv1 = *(const float4*)&bv[j0 + 4];
  float* Vp = ws + OFF_V + (size_t)row0 * DM;
  #pragma unroll
  for (int i = 0; i < 4; ++i) {
    float4 o0 = make_float4(acc[i][0] + bv0.x, acc[i][1] + bv0.y,
                            acc[i][2] + bv0.z, acc[i][3] + bv0.w);
    float4 o1 = make_float4(acc[i][4] + bv1.x, acc[i][5] + bv1.y,
                            acc[i][6] + bv1.z, acc[i][7] + bv1.w);
    *(float4*)&Vp[(size_t)(r0 + i) * DM + j0] = o0;
    *(float4*)&Vp[(size_t)(r0 + i) * DM + j0 + 4] = o1;
  }
}

// K2: per-edge logit -> exp -> atomic segment-sum over (b,dst); fused src-degree count
__global__ __launch_bounds__(256) void k2_edge1(const int* __restrict__ ei,
                                                const int* __restrict__ bidx,
                                                const float* __restrict__ eemb,
                                                float* __restrict__ ws) {
  __shared__ float wewa_s[DE];
  __shared__ float cb_s;
  int t = threadIdx.x;
  if (t < DE) wewa_s[t] = ws[OFF_WEWA + t];
  if (t == DE) cb_s = ws[OFF_CB];
  __syncthreads();
  int e = blockIdx.x * 256 + t;
  if (e >= kE) return;
  int s = ei[e];
  int d = ei[kE + e];
  int b = bidx[e];
  const float4* emb = (const float4*)(eemb + (size_t)e * DE);
  float a = 0.f;
  #pragma unroll
  for (int i = 0; i < 16; ++i) {
    float4 v = emb[i];
    a += v.x * wewa_s[i * 4] + v.y * wewa_s[i * 4 + 1] +
         v.z * wewa_s[i * 4 + 2] + v.w * wewa_s[i * 4 + 3];
  }
  float logit = (ws[OFF_QA + b * kN + s] + ws[OFF_KA + b * kN + d] + a + cb_s) * 0.25f;
  float ex = __expf(logit);
  ws[OFF_AEXP + e] = ex;
  unsafeAtomicAdd(&ws[OFF_ASUM + b * kN + d], ex);
  // CSR count by src
  int* wsi = (int*)ws;
  int gs = b * kN + s;
  wsi[OFF_POS + e] = atomicAdd(&wsi[OFF_CNT + gs], 1);
}

// scan step 1: block-local exclusive scan of cnt, block totals to bsum
__global__ __launch_bounds__(256) void k_scan1(float* __restrict__ ws) {
  __shared__ int sh[256];
  int* wsi = (int*)ws;
  const int tid = threadIdx.x;
  const int i = blockIdx.x * 256 + tid;
  int v = (i < kNodes) ? wsi[OFF_CNT + i] : 0;
  int acc = v;
  sh[tid] = acc;
  __syncthreads();
  #pragma unroll
  for (int ofs = 1; ofs < 256; ofs <<= 1) {
    int add = (tid >= ofs) ? sh[tid - ofs] : 0;
    __syncthreads();
    acc += add;
    sh[tid] = acc;
    __syncthreads();
  }
  if (i < kNodes) wsi[OFF_OFFS + i] = acc - v;
  if (tid == 255) wsi[OFF_BSUM + blockIdx.x] = acc;
}

// scan step 2: exclusive scan of block sums (782 <= 1024, single block)
__global__ __launch_bounds__(1024) void k_scan2(float* __restrict__ ws) {
  __shared__ int sh[1024];
  int* wsi = (int*)ws;
  const int tid = threadIdx.x;
  int v = (tid < kScanBlocks) ? wsi[OFF_BSUM + tid] : 0;
  int acc = v;
  sh[tid] = acc;
  __syncthreads();
  for (int ofs = 1; ofs < 1024; ofs <<= 1) {
    int add = (tid >= ofs) ? sh[tid - ofs] : 0;
    __syncthreads();
    acc += add;
    sh[tid] = acc;
    __syncthreads();
  }
  wsi[OFF_BPRE + tid] = acc - v;
}

// scan step 3: finalize global offsets in-place
__global__ __launch_bounds__(256) void k_scan3(float* __restrict__ ws) {
  int* wsi = (int*)ws;
  int i = blockIdx.x * 256 + threadIdx.x;
  if (i < kNodes) wsi[OFF_OFFS + i] += wsi[OFF_BPRE + (i >> 8)];
}

// fill: resolve each edge into its CSR slot as a 16B record {alpha, gd, e, pad}
__global__ __launch_bounds__(256) void k_fill(const int* __restrict__ ei,
                                              const int* __restrict__ bidx,
                                              float* __restrict__ ws) {
  int e = blockIdx.x * 256 + threadIdx.x;
  if (e >= kE) return;
  int s = ei[e];
  int d = ei[kE + e];
  int b = bidx[e];
  int gs = b * kN + s;
  int gd = b * kN + d;
  const int* wsi = (const int*)ws;
  float alpha = ws[OFF_AEXP + e] / (ws[OFF_ASUM + gd] + 1e-9f);
  int p = wsi[OFF_OFFS + gs] + wsi[OFF_POS + e];
  float4 r;
  r.x = alpha;
  r.y = __int_as_float(gd);
  r.z = __int_as_float(e);
  r.w = 0.f;
  ((float4*)(ws + OFF_REC))[p] = r;
}

// gather: one wave per node; out = sum(alpha*V[dst]) + (sum(alpha*emb))@Wev + sum(alpha)*bev
// Wev held in 128 VGPRs/lane; t_k broadcast via v_readlane (no DS pressure, no atomics).
__global__ __launch_bounds__(256) void k3_gather(const float* __restrict__ eemb,
                                                 const float* __restrict__ Wev,
                                                 const float* __restrict__ bev,
                                                 const float* __restrict__ ws,
                                                 float* __restrict__ out) {
  const int lane = threadIdx.x & 63;
  const int gw = (blockIdx.x * 256 + threadIdx.x) >> 6;
  const int nw = (gridDim.x * 256) >> 6;
  const int* wsi = (const int*)ws;
  const float* V = ws + OFF_V;
  const float4* rec = (const float4*)(ws + OFF_REC);

  float wr0[64], wr1[64];
  #pragma unroll
  for (int k = 0; k < 64; ++k) {
    wr0[k] = Wev[k * DM + lane];
    wr1[k] = Wev[k * DM + 64 + lane];
  }
  const float bev0 = bev[lane];
  const float bev1 = bev[64 + lane];

  for (int g = gw; g < kNodes; g += nw) {
    int start = wsi[OFF_OFFS + g];
    int deg = wsi[OFF_CNT + g];
    float o0 = 0.f, o1 = 0.f, tac = 0.f, ss = 0.f;
    for (int i = 0; i < deg; ++i) {
      float4 r = rec[start + i];
      float alpha = r.x;
      int gd = __float_as_int(r.y);
      int e = __float_as_int(r.z);
      o0 += alpha * V[(size_t)gd * DM + lane];
      o1 += alpha * V[(size_t)gd * DM + 64 + lane];
      tac += alpha * eemb[(size_t)e * DE + lane];
      ss += alpha;
    }
    // epilogue matvec: out += tac @ Wev + ss*bev (tac broadcast via readlane)
    #pragma unroll
    for (int k = 0; k < 64; ++k) {
      float tk = __int_as_float(__builtin_amdgcn_readlane(__float_as_int(tac), k));
      o0 += tk * wr0[k];
      o1 += tk * wr1[k];
    }
    o0 += ss * bev0;
    o1 += ss * bev1;
    out[(size_t)g * DM + lane] = o0;
    out[(size_t)g * DM + 64 + lane] = o1;
  }
}

extern "C" void kernel_launch(void* const* d_in, const int* in_sizes, int n_in,
                              void* d_out, int out_size, void* d_ws, size_t ws_size,
                              hipStream_t stream) {
  const float* x    = (const float*)d_in[0];
  const int*   ei   = (const int*)d_in[1];
  const float* eemb = (const float*)d_in[2];
  const int*   bidx = (const int*)d_in[3];
  // d_in[4] = n_heads (d_h = 16 -> scale 0.25 hard-coded)
  const float* Wq  = (const float*)d_in[5];
  const float* bq  = (const float*)d_in[6];
  const float* Wk  = (const float*)d_in[7];
  const float* bk  = (const float*)d_in[8];
  const float* Wv  = (const float*)d_in[9];
  const float* bv  = (const float*)d_in[10];
  const float* Wew = (const float*)d_in[11];
  const float* bew = (const float*)d_in[12];
  const float* Wev = (const float*)d_in[13];
  const float* bev = (const float*)d_in[14];
  const float* Wa  = (const float*)d_in[15];
  float* ws  = (float*)d_ws;
  float* out = (float*)d_out;

  // zero only the small accumulators: att_sum (fp32) and CSR counts (int)
  hipMemsetAsync(ws + OFF_ASUM, 0, (size_t)kNodes * sizeof(float), stream);
  hipMemsetAsync(ws + OFF_CNT, 0, (size_t)kNodes * sizeof(int), stream);

  k0_combine<<<1, 320, 0, stream>>>(Wq, Wk, Wew, Wa, bq, bk, bew, ws);
  k1_node<<<kNodes / 64, 256, 0, stream>>>(x, Wv, bv, ws);
  k2_edge1<<<(kE + 255) / 256, 256, 0, stream>>>(ei, bidx, eemb, ws);
  k_scan1<<<kScanBlocks, 256, 0, stream>>>(ws);
  k_scan2<<<1, 1024, 0, stream>>>(ws);
  k_scan3<<<kScanBlocks, 256, 0, stream>>>(ws);
  k_fill<<<(kE + 255) / 256, 256, 0, stream>>>(ei, bidx, ws);
  k3_gather<<<3072, 256, 0, stream>>>(eemb, Wev, bev, ws, out);
}

// Round 3
// 639.148 us; speedup vs baseline: 1.4447x; 1.1742x over previous
//
#include <hip/hip_runtime.h>

#define DM 128
#define DE 64

static constexpr int kB = 4;
static constexpr int kN = 50000;
static constexpr int kE = 600000;
static constexpr int kNodes = kB * kN;  // 200000

// workspace layout (float units; 4B-aligned ints share the arena)
static constexpr size_t OFF_V    = 0;                               // nodes x 128
static constexpr size_t OFF_T    = OFF_V + (size_t)kNodes * DM;     // nodes x 64
static constexpr size_t OFF_QA   = OFF_T + (size_t)kNodes * DE;     // nodes
static constexpr size_t OFF_KA   = OFF_QA + kNodes;                 // nodes
static constexpr size_t OFF_ASUM = OFF_KA + kNodes;                 // nodes
static constexpr size_t OFF_AEXP = OFF_ASUM + kNodes;               // edges
static constexpr size_t OFF_CNT  = OFF_AEXP + kE;                   // nodes (int)
static constexpr size_t OFF_OFFS = OFF_CNT + kNodes;                // nodes (int)
static constexpr size_t OFF_POS  = OFF_OFFS + kNodes;               // edges (int)
static constexpr size_t OFF_BSUM = OFF_POS + kE;                    // 1024 (int)
static constexpr size_t OFF_BPRE = OFF_BSUM + 1024;                 // 1024 (int)
static constexpr size_t OFF_REC  = OFF_BPRE + 1024;                 // edges x float4 (16B aligned)
static constexpr size_t OFF_WQA  = OFF_REC + (size_t)kE * 4;        // 128
static constexpr size_t OFF_WKA  = OFF_WQA + DM;                    // 128
static constexpr size_t OFF_WEWA = OFF_WKA + DM;                    // 64
static constexpr size_t OFF_CB   = OFF_WEWA + DE;                   // 1

static constexpr int kScanBlocks = (kNodes + 255) / 256;  // 782

// K0: fold Wa through the Q/K/Ew projections. wqa = Wq@Wa etc., cb = (bq+bk+bew)·Wa
__global__ void k0_combine(const float* __restrict__ Wq, const float* __restrict__ Wk,
                           const float* __restrict__ Wew, const float* __restrict__ Wa,
                           const float* __restrict__ bq, const float* __restrict__ bk,
                           const float* __restrict__ bew, float* __restrict__ ws) {
  int t = threadIdx.x;
  if (t < DM) {
    float a = 0.f;
    for (int j = 0; j < DM; ++j) a += Wq[t * DM + j] * Wa[j];
    ws[OFF_WQA + t] = a;
  } else if (t < 2 * DM) {
    int i = t - DM;
    float a = 0.f;
    for (int j = 0; j < DM; ++j) a += Wk[i * DM + j] * Wa[j];
    ws[OFF_WKA + i] = a;
  } else if (t < 2 * DM + DE) {
    int i = t - 2 * DM;
    float a = 0.f;
    for (int j = 0; j < DM; ++j) a += Wew[i * DM + j] * Wa[j];
    ws[OFF_WEWA + i] = a;
  }
  if (t == 0) {
    float a = 0.f;
    for (int j = 0; j < DM; ++j) a += (bq[j] + bk[j] + bew[j]) * Wa[j];
    ws[OFF_CB] = a;
  }
}

// K1: V = x@Wv + bv (200000x128x128), fused qa = x·wqa, ka = x·wka.
__global__ __launch_bounds__(256) void k1_node(const float* __restrict__ x,
                                               const float* __restrict__ Wv,
                                               const float* __restrict__ bv,
                                               float* __restrict__ ws) {
  __shared__ float xs[64][132];
  __shared__ float wvs[32][132];
  const int t = threadIdx.x;
  const int row0 = blockIdx.x * 64;

  const float4* xg = (const float4*)(x + (size_t)row0 * DM);
  #pragma unroll
  for (int i = 0; i < 8; ++i) {
    int idx = t + i * 256;
    int r = idx >> 5, c = (idx & 31) * 4;
    *(float4*)&xs[r][c] = xg[idx];
  }
  __syncthreads();

  if (t < 128) {
    const int r = t & 63;
    const float* wvec = (t < 64) ? (ws + OFF_WQA) : (ws + OFF_WKA);
    float a = 0.f;
    for (int k = 0; k < DM; k += 4) {
      a += xs[r][k] * wvec[k] + xs[r][k + 1] * wvec[k + 1] +
           xs[r][k + 2] * wvec[k + 2] + xs[r][k + 3] * wvec[k + 3];
    }
    float* dstp = (t < 64) ? (ws + OFF_QA) : (ws + OFF_KA);
    dstp[row0 + r] = a;
  }

  const int tx = t & 15, ty = t >> 4;
  const int j0 = tx * 8, r0 = ty * 4;
  float acc[4][8];
  #pragma unroll
  for (int i = 0; i < 4; ++i)
    #pragma unroll
    for (int j = 0; j < 8; ++j) acc[i][j] = 0.f;

  for (int kc = 0; kc < 4; ++kc) {
    __syncthreads();
    const float4* wg = (const float4*)(Wv + (size_t)kc * 32 * DM);
    #pragma unroll
    for (int i = 0; i < 4; ++i) {
      int idx = t + i * 256;
      int r = idx >> 5, c = (idx & 31) * 4;
      *(float4*)&wvs[r][c] = wg[idx];
    }
    __syncthreads();
    const int kb = kc * 32;
    #pragma unroll
    for (int kk = 0; kk < 32; kk += 4) {
      float xv[4][4];
      #pragma unroll
      for (int i = 0; i < 4; ++i) {
        float4 tmp = *(const float4*)&xs[r0 + i][kb + kk];
        xv[i][0] = tmp.x; xv[i][1] = tmp.y; xv[i][2] = tmp.z; xv[i][3] = tmp.w;
      }
      #pragma unroll
      for (int d = 0; d < 4; ++d) {
        float4 w0 = *(const float4*)&wvs[kk + d][j0];
        float4 w1 = *(const float4*)&wvs[kk + d][j0 + 4];
        float wj[8] = {w0.x, w0.y, w0.z, w0.w, w1.x, w1.y, w1.z, w1.w};
        #pragma unroll
        for (int i = 0; i < 4; ++i)
          #pragma unroll
          for (int j = 0; j < 8; ++j) acc[i][j] += xv[i][d] * wj[j];
      }
    }
  }

  const float4 bv0 = *(const float4*)&bv[j0];
  const float4 bv1 = *(const float4*)&bv[j0 + 4];
  float* Vp = ws + OFF_V + (size_t)row0 * DM;
  #pragma unroll
  for (int i = 0; i < 4; ++i) {
    float4 o0 = make_float4(acc[i][0] + bv0.x, acc[i][1] + bv0.y,
                            acc[i][2] + bv0.z, acc[i][3] + bv0.w);
    float4 o1 = make_float4(acc[i][4] + bv1.x, acc[i][5] + bv1.y,
                            acc[i][6] + bv1.z, acc[i][7] + bv1.w);
    *(float4*)&Vp[(size_t)(r0 + i) * DM + j0] = o0;
    *(float4*)&Vp[(size_t)(r0 + i) * DM + j0 + 4] = o1;
  }
}

// K2: per-edge logit -> exp -> atomic segment-sum over (b,dst); fused src-degree count
__global__ __launch_bounds__(256) void k2_edge1(const int* __restrict__ ei,
                                                const int* __restrict__ bidx,
                                                const float* __restrict__ eemb,
                                                float* __restrict__ ws) {
  __shared__ float wewa_s[DE];
  __shared__ float cb_s;
  int t = threadIdx.x;
  if (t < DE) wewa_s[t] = ws[OFF_WEWA + t];
  if (t == DE) cb_s = ws[OFF_CB];
  __syncthreads();
  int e = blockIdx.x * 256 + t;
  if (e >= kE) return;
  int s = ei[e];
  int d = ei[kE + e];
  int b = bidx[e];
  const float4* emb = (const float4*)(eemb + (size_t)e * DE);
  float a = 0.f;
  #pragma unroll
  for (int i = 0; i < 16; ++i) {
    float4 v = emb[i];
    a += v.x * wewa_s[i * 4] + v.y * wewa_s[i * 4 + 1] +
         v.z * wewa_s[i * 4 + 2] + v.w * wewa_s[i * 4 + 3];
  }
  float logit = (ws[OFF_QA + b * kN + s] + ws[OFF_KA + b * kN + d] + a + cb_s) * 0.25f;
  float ex = __expf(logit);
  ws[OFF_AEXP + e] = ex;
  unsafeAtomicAdd(&ws[OFF_ASUM + b * kN + d], ex);
  int* wsi = (int*)ws;
  int gs = b * kN + s;
  wsi[OFF_POS + e] = atomicAdd(&wsi[OFF_CNT + gs], 1);
}

// scan step 1: block-local exclusive scan of cnt, block totals to bsum
__global__ __launch_bounds__(256) void k_scan1(float* __restrict__ ws) {
  __shared__ int sh[256];
  int* wsi = (int*)ws;
  const int tid = threadIdx.x;
  const int i = blockIdx.x * 256 + tid;
  int v = (i < kNodes) ? wsi[OFF_CNT + i] : 0;
  int acc = v;
  sh[tid] = acc;
  __syncthreads();
  #pragma unroll
  for (int ofs = 1; ofs < 256; ofs <<= 1) {
    int add = (tid >= ofs) ? sh[tid - ofs] : 0;
    __syncthreads();
    acc += add;
    sh[tid] = acc;
    __syncthreads();
  }
  if (i < kNodes) wsi[OFF_OFFS + i] = acc - v;
  if (tid == 255) wsi[OFF_BSUM + blockIdx.x] = acc;
}

// scan step 2: exclusive scan of block sums (782 <= 1024, single block)
__global__ __launch_bounds__(1024) void k_scan2(float* __restrict__ ws) {
  __shared__ int sh[1024];
  int* wsi = (int*)ws;
  const int tid = threadIdx.x;
  int v = (tid < kScanBlocks) ? wsi[OFF_BSUM + tid] : 0;
  int acc = v;
  sh[tid] = acc;
  __syncthreads();
  for (int ofs = 1; ofs < 1024; ofs <<= 1) {
    int add = (tid >= ofs) ? sh[tid - ofs] : 0;
    __syncthreads();
    acc += add;
    sh[tid] = acc;
    __syncthreads();
  }
  wsi[OFF_BPRE + tid] = acc - v;
}

// scan step 3: finalize global offsets in-place
__global__ __launch_bounds__(256) void k_scan3(float* __restrict__ ws) {
  int* wsi = (int*)ws;
  int i = blockIdx.x * 256 + threadIdx.x;
  if (i < kNodes) wsi[OFF_OFFS + i] += wsi[OFF_BPRE + (i >> 8)];
}

// fill: resolve each edge into its CSR slot as a 16B record {alpha, gd, e, pad}
__global__ __launch_bounds__(256) void k_fill(const int* __restrict__ ei,
                                              const int* __restrict__ bidx,
                                              float* __restrict__ ws) {
  int e = blockIdx.x * 256 + threadIdx.x;
  if (e >= kE) return;
  int s = ei[e];
  int d = ei[kE + e];
  int b = bidx[e];
  int gs = b * kN + s;
  int gd = b * kN + d;
  const int* wsi = (const int*)ws;
  float alpha = ws[OFF_AEXP + e] / (ws[OFF_ASUM + gd] + 1e-9f);
  int p = wsi[OFF_OFFS + gs] + wsi[OFF_POS + e];
  float4 r;
  r.x = alpha;
  r.y = __int_as_float(gd);
  r.z = __int_as_float(e);
  r.w = 0.f;
  ((float4*)(ws + OFF_REC))[p] = r;
}

// gather: one wave per node, 4 edges per round with all 12 gathers in flight.
// out1 = sum(alpha*V[dst]) + ss*bev ; T = sum(alpha*emb). Wev matvec deferred to k4.
__global__ __launch_bounds__(256) void k3_gather(const float* __restrict__ eemb,
                                                 const float* __restrict__ bev,
                                                 float* __restrict__ ws,
                                                 float* __restrict__ out) {
  const int lane = threadIdx.x & 63;
  const int gw = (blockIdx.x * 256 + threadIdx.x) >> 6;
  const int nw = (gridDim.x * 256) >> 6;
  const int* wsi = (const int*)ws;
  const float* V = ws + OFF_V;
  float* T = ws + OFF_T;
  const float4* rec = (const float4*)(ws + OFF_REC);
  const float bev0 = bev[lane];
  const float bev1 = bev[64 + lane];

  for (int g = gw; g < kNodes; g += nw) {
    const int start = wsi[OFF_OFFS + g];
    const int deg = wsi[OFF_CNT + g];
    float o0 = 0.f, o1 = 0.f, tac = 0.f, ss = 0.f;
    for (int base = 0; base < deg; base += 4) {
      const int rem = deg - base;  // >= 1, wave-uniform
      const int c1 = (rem > 1) ? 1 : 0;
      const int c2 = (rem > 2) ? 2 : c1;
      const int c3 = (rem > 3) ? 3 : c2;
      // contiguous rec loads, clamped (duplicates hit L1)
      float4 r0 = rec[start + base];
      float4 r1 = rec[start + base + c1];
      float4 r2 = rec[start + base + c2];
      float4 r3 = rec[start + base + c3];
      float a0 = r0.x;
      float a1 = (rem > 1) ? r1.x : 0.f;
      float a2 = (rem > 2) ? r2.x : 0.f;
      float a3 = (rem > 3) ? r3.x : 0.f;
      const size_t gd0 = (size_t)__float_as_int(r0.y) * DM;
      const size_t gd1 = (size_t)__float_as_int(r1.y) * DM;
      const size_t gd2 = (size_t)__float_as_int(r2.y) * DM;
      const size_t gd3 = (size_t)__float_as_int(r3.y) * DM;
      const size_t e0 = (size_t)__float_as_int(r0.z) * DE;
      const size_t e1 = (size_t)__float_as_int(r1.z) * DE;
      const size_t e2 = (size_t)__float_as_int(r2.z) * DE;
      const size_t e3 = (size_t)__float_as_int(r3.z) * DE;
      // 12 independent gathers in flight
      float v00 = V[gd0 + lane],      v01 = V[gd1 + lane];
      float v02 = V[gd2 + lane],      v03 = V[gd3 + lane];
      float v10 = V[gd0 + 64 + lane], v11 = V[gd1 + 64 + lane];
      float v12 = V[gd2 + 64 + lane], v13 = V[gd3 + 64 + lane];
      float m0 = eemb[e0 + lane],     m1 = eemb[e1 + lane];
      float m2 = eemb[e2 + lane],     m3 = eemb[e3 + lane];
      o0 += a0 * v00 + a1 * v01 + a2 * v02 + a3 * v03;
      o1 += a0 * v10 + a1 * v11 + a2 * v12 + a3 * v13;
      tac += a0 * m0 + a1 * m1 + a2 * m2 + a3 * m3;
      ss += a0 + a1 + a2 + a3;
    }
    out[(size_t)g * DM + lane] = o0 + ss * bev0;
    out[(size_t)g * DM + 64 + lane] = o1 + ss * bev1;
    T[(size_t)g * DE + lane] = tac;
  }
}

// K4: out += T@Wev  (200000x64x128 GEMM, added in-place)
__global__ __launch_bounds__(256) void k4_wev(const float* __restrict__ Wev,
                                              float* __restrict__ ws,
                                              float* __restrict__ out) {
  __shared__ float ts[64][68];
  __shared__ float wes[64][132];
  const int t = threadIdx.x;
  const int row0 = blockIdx.x * 64;
  const float* T = ws + OFF_T;

  const float4* tg = (const float4*)(T + (size_t)row0 * DE);
  #pragma unroll
  for (int i = 0; i < 4; ++i) {
    int idx = t + i * 256;
    int r = idx >> 4, c = (idx & 15) * 4;
    *(float4*)&ts[r][c] = tg[idx];
  }
  const float4* wg = (const float4*)Wev;
  #pragma unroll
  for (int i = 0; i < 8; ++i) {
    int idx = t + i * 256;
    int r = idx >> 5, c = (idx & 31) * 4;
    *(float4*)&wes[r][c] = wg[idx];
  }
  __syncthreads();

  const int tx = t & 15, ty = t >> 4;
  const int j0 = tx * 8, r0 = ty * 4;
  float acc[4][8];
  #pragma unroll
  for (int i = 0; i < 4; ++i)
    #pragma unroll
    for (int j = 0; j < 8; ++j) acc[i][j] = 0.f;

  #pragma unroll
  for (int kk = 0; kk < DE; kk += 4) {
    float xv[4][4];
    #pragma unroll
    for (int i = 0; i < 4; ++i) {
      float4 tmp = *(const float4*)&ts[r0 + i][kk];
      xv[i][0] = tmp.x; xv[i][1] = tmp.y; xv[i][2] = tmp.z; xv[i][3] = tmp.w;
    }
    #pragma unroll
    for (int d = 0; d < 4; ++d) {
      float4 w0 = *(const float4*)&wes[kk + d][j0];
      float4 w1 = *(const float4*)&wes[kk + d][j0 + 4];
      float wj[8] = {w0.x, w0.y, w0.z, w0.w, w1.x, w1.y, w1.z, w1.w};
      #pragma unroll
      for (int i = 0; i < 4; ++i)
        #pragma unroll
        for (int j = 0; j < 8; ++j) acc[i][j] += xv[i][d] * wj[j];
    }
  }

  #pragma unroll
  for (int i = 0; i < 4; ++i) {
    size_t g = (size_t)(row0 + r0 + i);
    float4 o0 = *(const float4*)&out[g * DM + j0];
    float4 o1 = *(const float4*)&out[g * DM + j0 + 4];
    o0.x += acc[i][0]; o0.y += acc[i][1]; o0.z += acc[i][2]; o0.w += acc[i][3];
    o1.x += acc[i][4]; o1.y += acc[i][5]; o1.z += acc[i][6]; o1.w += acc[i][7];
    *(float4*)&out[g * DM + j0] = o0;
    *(float4*)&out[g * DM + j0 + 4] = o1;
  }
}

extern "C" void kernel_launch(void* const* d_in, const int* in_sizes, int n_in,
                              void* d_out, int out_size, void* d_ws, size_t ws_size,
                              hipStream_t stream) {
  const float* x    = (const float*)d_in[0];
  const int*   ei   = (const int*)d_in[1];
  const float* eemb = (const float*)d_in[2];
  const int*   bidx = (const int*)d_in[3];
  // d_in[4] = n_heads (d_h = 16 -> scale 0.25 hard-coded)
  const float* Wq  = (const float*)d_in[5];
  const float* bq  = (const float*)d_in[6];
  const float* Wk  = (const float*)d_in[7];
  const float* bk  = (const float*)d_in[8];
  const float* Wv  = (const float*)d_in[9];
  const float* bv  = (const float*)d_in[10];
  const float* Wew = (const float*)d_in[11];
  const float* bew = (const float*)d_in[12];
  const float* Wev = (const float*)d_in[13];
  const float* bev = (const float*)d_in[14];
  const float* Wa  = (const float*)d_in[15];
  float* ws  = (float*)d_ws;
  float* out = (float*)d_out;

  hipMemsetAsync(ws + OFF_ASUM, 0, (size_t)kNodes * sizeof(float), stream);
  hipMemsetAsync(ws + OFF_CNT, 0, (size_t)kNodes * sizeof(int), stream);

  k0_combine<<<1, 320, 0, stream>>>(Wq, Wk, Wew, Wa, bq, bk, bew, ws);
  k1_node<<<kNodes / 64, 256, 0, stream>>>(x, Wv, bv, ws);
  k2_edge1<<<(kE + 255) / 256, 256, 0, stream>>>(ei, bidx, eemb, ws);
  k_scan1<<<kScanBlocks, 256, 0, stream>>>(ws);
  k_scan2<<<1, 1024, 0, stream>>>(ws);
  k_scan3<<<kScanBlocks, 256, 0, stream>>>(ws);
  k_fill<<<(kE + 255) / 256, 256, 0, stream>>>(ei, bidx, ws);
  k3_gather<<<4096, 256, 0, stream>>>(eemb, bev, ws, out);
  k4_wev<<<kNodes / 64, 256, 0, stream>>>(Wev, ws, out);
}